// Round 5
// baseline (2512.064 us; speedup 1.0000x reference)
//
#include <hip/hip_runtime.h>
#include <cstdint>
#include <cstddef>

#define NTOK 4096
#define DMODEL 1024
#define NHEAD 8
#define DHEAD 128
#define DFFN 1536
#define LNEPS 1e-5f

typedef __bf16 bf16_t;
typedef __bf16 bf16x8 __attribute__((ext_vector_type(8)));
typedef __bf16 bf16x4 __attribute__((ext_vector_type(4)));
typedef float f32x4 __attribute__((ext_vector_type(4)));
typedef float f32x16 __attribute__((ext_vector_type(16)));

__device__ __forceinline__ void gload_lds16(const bf16_t* g, bf16_t* lds) {
  __builtin_amdgcn_global_load_lds(
      (const __attribute__((address_space(1))) unsigned int*)g,
      (__attribute__((address_space(3))) unsigned int*)lds, 16, 0, 0);
}

__device__ __forceinline__ unsigned pkbf(float lo, float hi) {
  unsigned a = (unsigned)__builtin_bit_cast(unsigned short, (bf16_t)lo);
  unsigned b = (unsigned)__builtin_bit_cast(unsigned short, (bf16_t)hi);
  return (b << 16) | a;
}

// ---------------- f32 -> bf16 convert ----------------
__global__ __launch_bounds__(256) void cvt_kernel(const float* __restrict__ in,
                                                  bf16_t* __restrict__ out, int n4) {
  int i = blockIdx.x * 256 + threadIdx.x;
  if (i < n4) {
    const float4 v = reinterpret_cast<const float4*>(in)[i];
    bf16x4 o = {(bf16_t)v.x, (bf16_t)v.y, (bf16_t)v.z, (bf16_t)v.w};
    reinterpret_cast<bf16x4*>(out)[i] = o;
  }
}

// ---------------- int2 coords -> float2 ----------------
__global__ __launch_bounds__(256) void cvtc_kernel(const int* __restrict__ in,
                                                   float2* __restrict__ out, int n) {
  int i = blockIdx.x * 256 + threadIdx.x;
  if (i < n) {
    int2 c = reinterpret_cast<const int2*>(in)[i];
    out[i] = make_float2((float)c.x, (float)c.y);
  }
}

// ---------------- bf16 GEMM, C = A @ B^T (+ epilogue) ----------------
template<int EPI>
__global__ __launch_bounds__(256) void gemm_bt(
    const bf16_t* __restrict__ A, const bf16_t* __restrict__ B,
    int M, int Nn, int K,
    const float* __restrict__ bias, const float* __restrict__ resid,
    float* __restrict__ outF, bf16_t* __restrict__ outH)
{
  __shared__ bf16_t As[128 * 32];
  __shared__ bf16_t Bs[128 * 32];
  const int t = threadIdx.x;
  const int w = t >> 6, l = t & 63;
  const int lg = l >> 4, li = l & 15;
  const int m0 = blockIdx.x * 128, n0 = blockIdx.y * 128;
  const int wr = (w >> 1) * 64, wc = (w & 1) * 64;
  const f32x4 fz = {0.f, 0.f, 0.f, 0.f};
  f32x4 acc[4][4];
#pragma unroll
  for (int i = 0; i < 4; i++)
#pragma unroll
    for (int j = 0; j < 4; j++) acc[i][j] = fz;

  const bf16_t* Ag = A + (size_t)m0 * K;
  const bf16_t* Bg = B + (size_t)n0 * K;

  for (int kt = 0; kt < K; kt += 32) {
    if (kt) __syncthreads();
#pragma unroll
    for (int p = 0; p < 2; p++) {
      int c = p * 256 + w * 64 + l;
      gload_lds16(Ag + (size_t)(c >> 2) * K + kt + (c & 3) * 8,
                  As + (p * 256 + w * 64) * 8);
      gload_lds16(Bg + (size_t)(c >> 2) * K + kt + (c & 3) * 8,
                  Bs + (p * 256 + w * 64) * 8);
    }
    __syncthreads();
    bf16x8 af[4], bfr[4];
#pragma unroll
    for (int mi = 0; mi < 4; mi++)
      af[mi] = *reinterpret_cast<const bf16x8*>(&As[(wr + mi * 16 + li) * 32 + lg * 8]);
#pragma unroll
    for (int ni = 0; ni < 4; ni++)
      bfr[ni] = *reinterpret_cast<const bf16x8*>(&Bs[(wc + ni * 16 + li) * 32 + lg * 8]);
#pragma unroll
    for (int mi = 0; mi < 4; mi++)
#pragma unroll
      for (int ni = 0; ni < 4; ni++)
        acc[mi][ni] = __builtin_amdgcn_mfma_f32_16x16x32_bf16(af[mi], bfr[ni], acc[mi][ni], 0, 0, 0);
  }

#pragma unroll
  for (int mi = 0; mi < 4; mi++) {
#pragma unroll
    for (int ni = 0; ni < 4; ni++) {
      int gcol = n0 + wc + ni * 16 + li;
#pragma unroll
      for (int r = 0; r < 4; r++) {
        int grow = m0 + wr + mi * 16 + lg * 4 + r;
        float v = acc[mi][ni][r];
        if (EPI == 0) {
          outH[(size_t)grow * Nn + gcol] = (bf16_t)v;
        } else if (EPI == 1) {
          v += bias[gcol] + resid[(size_t)grow * Nn + gcol];
          outF[(size_t)grow * Nn + gcol] = v;
        } else if (EPI == 2) {
          v += bias[gcol];
          v = 0.5f * v * (1.f + erff(v * 0.70710678118654752f));
          outH[(size_t)grow * Nn + gcol] = (bf16_t)v;
        } else {
          v += bias[gcol] + resid[(size_t)grow * Nn + gcol];
          outF[(size_t)grow * Nn + gcol] = v;
        }
      }
    }
  }
}

// ---------------- bf16 transpose [NTOK,DMODEL] -> [DMODEL,NTOK] ----------------
__global__ __launch_bounds__(256) void transpose_kernel(const bf16_t* __restrict__ in,
                                                        bf16_t* __restrict__ out)
{
  __shared__ bf16_t tile[64][72];
  int t = threadIdx.x;
  int nb = blockIdx.x * 64, db = blockIdx.y * 64;
#pragma unroll
  for (int p = 0; p < 2; p++) {
    int c = p * 256 + t;
    int n = c >> 3, cb = c & 7;
    bf16x8 v = *reinterpret_cast<const bf16x8*>(in + (size_t)(nb + n) * DMODEL + db + cb * 8);
    *reinterpret_cast<bf16x8*>(&tile[n][cb * 8]) = v;
  }
  __syncthreads();
#pragma unroll
  for (int p = 0; p < 2; p++) {
    int c = p * 256 + t;
    int d = c >> 3, nc = (c & 7) * 8;
    bf16x8 vv;
#pragma unroll
    for (int j = 0; j < 8; j++) vv[j] = tile[nc + j][d];
    *reinterpret_cast<bf16x8*>(out + (size_t)(db + d) * NTOK + nb + nc) = vv;
  }
}

// ---------------- fused dual-softmax flash attention, v4 ----------------
// Same math as v3 (no-LDS main loop, swapped QK^T, shfl P-redistribution),
// plus: float2 coords table, 17.4KB epilogue LDS (3-pass reuse of one
// buffer) so LDS allows 9 blocks/CU, __launch_bounds__(128,4) for 4
// waves/SIMD -> target 16 waves/CU.
__global__ __launch_bounds__(128, 4) void attn4_kernel(
    const bf16_t* __restrict__ Q, const bf16_t* __restrict__ K,
    const bf16_t* __restrict__ Vt, const float2* __restrict__ cf,
    bf16_t* __restrict__ out)
{
  __shared__ float buf[128 * 33];   // 16.9KB, reused in 3 epilogue passes
  __shared__ float mlS[4][32];

  const int t = threadIdx.x;
  const int w = t >> 6;
  const int l = t & 63;
  const int q5 = l & 31;
  const int hi = l >> 5;
  const int h = blockIdx.x & 7;
  const int q0 = (blockIdx.x >> 3) * 32;
  const float LOG2E = 1.44269504088896f;
  const float isq = 0.08838834764831845f;   // 1/sqrt(128)
  const float itau = 1.6666666666666667f;   // 1/0.6
  const float hs = 1.0f / (float)(2 << h);
  const float ap = isq * LOG2E;
  const float an = -isq * itau * LOG2E;
  const float bpp = hs * LOG2E;
  const float bnp = hs * itau * LOG2E;

  // preload Q fragments (B-operand: col q = lane&31, k = d = 16c + 8hi + j)
  bf16x8 qf[8];
  {
    const bf16_t* qrow = Q + (size_t)(q0 + q5) * DMODEL + h * DHEAD;
#pragma unroll
    for (int c = 0; c < 8; c++)
      qf[c] = *reinterpret_cast<const bf16x8*>(qrow + c * 16 + hi * 8);
  }
  const float2 qc = cf[q0 + q5];
  const float qx = qc.x, qy = qc.y;

  f32x16 accp[4], accn[4];
#pragma unroll
  for (int f = 0; f < 4; f++) {
#pragma unroll
    for (int r = 0; r < 16; r++) { accp[f][r] = 0.f; accn[f][r] = 0.f; }
  }
  float mp = -3e38f, mn = -3e38f, lp = 0.f, lN = 0.f;

  const bf16_t* krow = K + (size_t)(w * 2048 + q5) * DMODEL + h * DHEAD + hi * 8;
  const bf16_t* vrow0 = Vt + (size_t)(h * DHEAD + q5) * NTOK + w * 2048 + hi * 8;

  for (int it = 0; it < 64; it++) {
    const int kv0 = w * 2048 + it * 32;

    // ---- issue K-frag loads (direct global; row kv0+q5) ----
    bf16x8 kf[8];
    {
      const bf16_t* kp = krow + (size_t)it * 32 * DMODEL;
#pragma unroll
      for (int c = 0; c < 8; c++)
        kf[c] = *reinterpret_cast<const bf16x8*>(kp + c * 16);
    }

    // ---- bias distances while K loads are in flight ----
    float br[16];
#pragma unroll
    for (int r = 0; r < 16; r++) {
      int kvr = kv0 + (r & 3) + 8 * (r >> 2) + 4 * hi;
      float2 c = cf[kvr];
      float dx = qx - c.x, dy = qy - c.y;
      br[r] = sqrtf(dx * dx + dy * dy);
    }

    // ---- S^T = K * Q^T (32 kv x 32 q) ----
    f32x16 sacc;
#pragma unroll
    for (int r = 0; r < 16; r++) sacc[r] = 0.f;
#pragma unroll
    for (int c = 0; c < 8; c++)
      sacc = __builtin_amdgcn_mfma_f32_32x32x16_bf16(kf[c], qf[c], sacc, 0, 0, 0);

    // ---- issue V-frag loads (used after softmax; latency hidden) ----
    bf16x8 vf[8];
#pragma unroll
    for (int ks = 0; ks < 2; ks++)
#pragma unroll
      for (int f = 0; f < 4; f++)
        vf[ks * 4 + f] = *reinterpret_cast<const bf16x8*>(
            vrow0 + (size_t)(32 * f) * NTOK + it * 32 + ks * 16);

    // ---- dual online softmax in log2 domain ----
    float p16[16], n16[16];
#pragma unroll
    for (int r = 0; r < 16; r++) {
      p16[r] = sacc[r] * ap - br[r] * bpp;
      n16[r] = sacc[r] * an - br[r] * bnp;
    }
    float tp, tn;
    {
      float a0 = fmaxf(fmaxf(p16[0], p16[1]), fmaxf(p16[2], p16[3]));
      float a1 = fmaxf(fmaxf(p16[4], p16[5]), fmaxf(p16[6], p16[7]));
      float a2 = fmaxf(fmaxf(p16[8], p16[9]), fmaxf(p16[10], p16[11]));
      float a3 = fmaxf(fmaxf(p16[12], p16[13]), fmaxf(p16[14], p16[15]));
      tp = fmaxf(fmaxf(a0, a1), fmaxf(a2, a3));
      float b0 = fmaxf(fmaxf(n16[0], n16[1]), fmaxf(n16[2], n16[3]));
      float b1 = fmaxf(fmaxf(n16[4], n16[5]), fmaxf(n16[6], n16[7]));
      float b2 = fmaxf(fmaxf(n16[8], n16[9]), fmaxf(n16[10], n16[11]));
      float b3 = fmaxf(fmaxf(n16[12], n16[13]), fmaxf(n16[14], n16[15]));
      tn = fmaxf(fmaxf(b0, b1), fmaxf(b2, b3));
    }
    tp = fmaxf(tp, __shfl_xor(tp, 32, 64));
    tn = fmaxf(tn, __shfl_xor(tn, 32, 64));

    if (__any((tp > mp + 8.f) || (tn > mn + 8.f))) {
      float mpn = fmaxf(mp, tp), mnn = fmaxf(mn, tn);
      float cp = exp2f(mp - mpn), cn = exp2f(mn - mnn);
      mp = mpn; mn = mnn; lp *= cp; lN *= cn;
#pragma unroll
      for (int f = 0; f < 4; f++) {
#pragma unroll
        for (int r = 0; r < 16; r++) { accp[f][r] *= cp; accn[f][r] *= cn; }
      }
    }
    float rp = 0.f, rn = 0.f;
#pragma unroll
    for (int r = 0; r < 16; r++) {
      p16[r] = exp2f(p16[r] - mp); rp += p16[r];
      n16[r] = exp2f(n16[r] - mn); rn += n16[r];
    }
    rp += __shfl_xor(rp, 32, 64);
    rn += __shfl_xor(rn, 32, 64);
    lp += rp; lN += rn;

    // ---- pack P^T to bf16 B-frags, redistribute via shfl_xor(32) ----
    unsigned pw[2][4], nw[2][4];
#pragma unroll
    for (int ks = 0; ks < 2; ks++) {
#pragma unroll
      for (int u = 0; u < 2; u++) {
        unsigned A = pkbf(p16[8 * ks + 2 * u], p16[8 * ks + 2 * u + 1]);
        unsigned B = pkbf(p16[8 * ks + 4 + 2 * u], p16[8 * ks + 4 + 2 * u + 1]);
        unsigned Ax = __shfl_xor(A, 32, 64);
        unsigned Bx = __shfl_xor(B, 32, 64);
        pw[ks][u] = hi ? Bx : A;
        pw[ks][2 + u] = hi ? B : Ax;
        unsigned C = pkbf(n16[8 * ks + 2 * u], n16[8 * ks + 2 * u + 1]);
        unsigned D = pkbf(n16[8 * ks + 4 + 2 * u], n16[8 * ks + 4 + 2 * u + 1]);
        unsigned Cx = __shfl_xor(C, 32, 64);
        unsigned Dx = __shfl_xor(D, 32, 64);
        nw[ks][u] = hi ? Dx : C;
        nw[ks][2 + u] = hi ? D : Cx;
      }
    }

    // ---- PV: O^T += V^T * P^T ----
#pragma unroll
    for (int ks = 0; ks < 2; ks++) {
      union { unsigned u[4]; bf16x8 v; } pb, nb;
#pragma unroll
      for (int j = 0; j < 4; j++) { pb.u[j] = pw[ks][j]; nb.u[j] = nw[ks][j]; }
#pragma unroll
      for (int f = 0; f < 4; f++) {
        accp[f] = __builtin_amdgcn_mfma_f32_32x32x16_bf16(vf[ks * 4 + f], pb.v, accp[f], 0, 0, 0);
        accn[f] = __builtin_amdgcn_mfma_f32_32x32x16_bf16(vf[ks * 4 + f], nb.v, accn[f], 0, 0, 0);
      }
    }
  }

  // ---- cross-wave combine (kv half 0 + half 1), one reused 16.9KB buffer ----
  __syncthreads();
  if (w == 1) {
    if (hi == 0) { mlS[0][q5] = mp; mlS[1][q5] = lp; mlS[2][q5] = mn; mlS[3][q5] = lN; }
#pragma unroll
    for (int f = 0; f < 4; f++)
#pragma unroll
      for (int r = 0; r < 16; r++)
        buf[(32 * f + (r & 3) + 8 * (r >> 2) + 4 * hi) * 33 + q5] = accp[f][r];
  }
  __syncthreads();
  float mp1 = mlS[0][q5], lp1 = mlS[1][q5], mn1 = mlS[2][q5], ln1 = mlS[3][q5];
  if (w == 0) {
    float mpc = fmaxf(mp, mp1);
    float e0 = exp2f(mp - mpc), e1 = exp2f(mp1 - mpc);
    lp = lp * e0 + lp1 * e1;
#pragma unroll
    for (int f = 0; f < 4; f++)
#pragma unroll
      for (int r = 0; r < 16; r++)
        accp[f][r] = accp[f][r] * e0 +
                     buf[(32 * f + (r & 3) + 8 * (r >> 2) + 4 * hi) * 33 + q5] * e1;
  }
  __syncthreads();
  if (w == 1) {
#pragma unroll
    for (int f = 0; f < 4; f++)
#pragma unroll
      for (int r = 0; r < 16; r++)
        buf[(32 * f + (r & 3) + 8 * (r >> 2) + 4 * hi) * 33 + q5] = accn[f][r];
  }
  __syncthreads();
  if (w == 0) {
    float mnc = fmaxf(mn, mn1);
    float e0 = exp2f(mn - mnc), e1 = exp2f(mn1 - mnc);
    lN = lN * e0 + ln1 * e1;
    float ip = 1.f / lp, inn = 1.5f / lN;
#pragma unroll
    for (int f = 0; f < 4; f++)
#pragma unroll
      for (int r = 0; r < 16; r++) {
        int row = 32 * f + (r & 3) + 8 * (r >> 2) + 4 * hi;
        float an2 = accn[f][r] * e0 + buf[row * 33 + q5] * e1;
        buf[row * 33 + q5] = accp[f][r] * ip - an2 * inn;
      }
  }
  __syncthreads();

  // ---- transpose store: thread t -> q = t>>2, d-quarter = (t&3)*32 ----
  {
    int q = t >> 2, dq = (t & 3) * 32;
#pragma unroll
    for (int j = 0; j < 4; j++) {
      bf16x8 ov;
#pragma unroll
      for (int e = 0; e < 8; e++) ov[e] = (bf16_t)buf[(dq + j * 8 + e) * 33 + q];
      *reinterpret_cast<bf16x8*>(out + (size_t)(q0 + q) * DMODEL + h * DHEAD + dq + j * 8) = ov;
    }
  }
}

// ---------------- row LayerNorm (D=1024) ----------------
__global__ __launch_bounds__(256) void ln_kernel(
    const float* __restrict__ in, const float* __restrict__ g, const float* __restrict__ b,
    float* __restrict__ outF, bf16_t* __restrict__ outH)
{
  int row = blockIdx.x, t = threadIdx.x;
  const float4 v = reinterpret_cast<const float4*>(in + (size_t)row * DMODEL)[t];
  float s = v.x + v.y + v.z + v.w;
  float ss = v.x * v.x + v.y * v.y + v.z * v.z + v.w * v.w;
#pragma unroll
  for (int m = 32; m >= 1; m >>= 1) {
    s += __shfl_xor(s, m, 64);
    ss += __shfl_xor(ss, m, 64);
  }
  __shared__ float red[8];
  int w = t >> 6, l = t & 63;
  if (l == 0) { red[w] = s; red[4 + w] = ss; }
  __syncthreads();
  s = red[0] + red[1] + red[2] + red[3];
  ss = red[4] + red[5] + red[6] + red[7];
  float mu = s * (1.f / DMODEL);
  float var = ss * (1.f / DMODEL) - mu * mu;
  float rs = rsqrtf(var + LNEPS);
  const float4 gv = reinterpret_cast<const float4*>(g)[t];
  const float4 bv = reinterpret_cast<const float4*>(b)[t];
  float y0 = (v.x - mu) * rs * gv.x + bv.x;
  float y1 = (v.y - mu) * rs * gv.y + bv.y;
  float y2 = (v.z - mu) * rs * gv.z + bv.z;
  float y3 = (v.w - mu) * rs * gv.w + bv.w;
  if (outF) {
    float4 o; o.x = y0; o.y = y1; o.z = y2; o.w = y3;
    reinterpret_cast<float4*>(outF + (size_t)row * DMODEL)[t] = o;
  }
  if (outH) {
    bf16x4 o = {(bf16_t)y0, (bf16_t)y1, (bf16_t)y2, (bf16_t)y3};
    reinterpret_cast<bf16x4*>(outH + (size_t)row * DMODEL)[t] = o;
  }
}

extern "C" void kernel_launch(void* const* d_in, const int* in_sizes, int n_in,
                              void* d_out, int out_size, void* d_ws, size_t ws_size,
                              hipStream_t stream) {
  (void)in_sizes; (void)n_in; (void)out_size; (void)ws_size;
  const float* features = (const float*)d_in[0];
  const int* coords = (const int*)d_in[1];
  const float* Wq = (const float*)d_in[2];
  const float* Wk = (const float*)d_in[3];
  const float* Wv = (const float*)d_in[4];
  const float* Wo = (const float*)d_in[5];
  const float* bo = (const float*)d_in[6];
  const float* ln1g = (const float*)d_in[7];
  const float* ln1b = (const float*)d_in[8];
  const float* W1 = (const float*)d_in[9];
  const float* b1 = (const float*)d_in[10];
  const float* W2 = (const float*)d_in[11];
  const float* b2 = (const float*)d_in[12];
  const float* ln2g = (const float*)d_in[13];
  const float* ln2b = (const float*)d_in[14];
  float* outp = (float*)d_out;

  char* ws = (char*)d_ws;
  size_t off = 0;
  auto alloc = [&](size_t bytes) -> void* {
    void* p = ws + off;
    off += (bytes + 255) & ~((size_t)255);
    return p;
  };
  bf16_t* fb16 = (bf16_t*)alloc((size_t)NTOK * DMODEL * 2);
  bf16_t* wq16 = (bf16_t*)alloc((size_t)DMODEL * DMODEL * 2);
  bf16_t* wk16 = (bf16_t*)alloc((size_t)DMODEL * DMODEL * 2);
  bf16_t* wv16 = (bf16_t*)alloc((size_t)DMODEL * DMODEL * 2);
  bf16_t* wo16 = (bf16_t*)alloc((size_t)DMODEL * DMODEL * 2);
  bf16_t* w116 = (bf16_t*)alloc((size_t)DFFN * DMODEL * 2);
  bf16_t* w216 = (bf16_t*)alloc((size_t)DMODEL * DFFN * 2);
  bf16_t* q16 = (bf16_t*)alloc((size_t)NTOK * DMODEL * 2);
  bf16_t* k16 = (bf16_t*)alloc((size_t)NTOK * DMODEL * 2);
  bf16_t* v16 = (bf16_t*)alloc((size_t)NTOK * DMODEL * 2);
  bf16_t* vt16 = (bf16_t*)alloc((size_t)NTOK * DMODEL * 2);
  float* acc1 = (float*)alloc((size_t)NTOK * DMODEL * 4);
  float* xf = (float*)alloc((size_t)NTOK * DMODEL * 4);
  bf16_t* x16 = (bf16_t*)alloc((size_t)NTOK * DMODEL * 2);
  bf16_t* h16 = (bf16_t*)alloc((size_t)NTOK * DFFN * 2);
  float2* cfl = (float2*)alloc((size_t)NTOK * sizeof(float2));
  bf16_t* att16 = fb16;

  cvt_kernel<<<dim3(NTOK * DMODEL / 1024), 256, 0, stream>>>(features, fb16, NTOK * DMODEL / 4);
  cvt_kernel<<<dim3(DMODEL * DMODEL / 1024), 256, 0, stream>>>(Wq, wq16, DMODEL * DMODEL / 4);
  cvt_kernel<<<dim3(DMODEL * DMODEL / 1024), 256, 0, stream>>>(Wk, wk16, DMODEL * DMODEL / 4);
  cvt_kernel<<<dim3(DMODEL * DMODEL / 1024), 256, 0, stream>>>(Wv, wv16, DMODEL * DMODEL / 4);
  cvt_kernel<<<dim3(DMODEL * DMODEL / 1024), 256, 0, stream>>>(Wo, wo16, DMODEL * DMODEL / 4);
  cvt_kernel<<<dim3(DFFN * DMODEL / 1024), 256, 0, stream>>>(W1, w116, DFFN * DMODEL / 4);
  cvt_kernel<<<dim3(DMODEL * DFFN / 1024), 256, 0, stream>>>(W2, w216, DMODEL * DFFN / 4);
  cvtc_kernel<<<dim3(NTOK / 256), 256, 0, stream>>>(coords, cfl, NTOK);

  dim3 gQKV(NTOK / 128, DMODEL / 128);
  gemm_bt<0><<<gQKV, 256, 0, stream>>>(fb16, wq16, NTOK, DMODEL, DMODEL, nullptr, nullptr, nullptr, q16);
  gemm_bt<0><<<gQKV, 256, 0, stream>>>(fb16, wk16, NTOK, DMODEL, DMODEL, nullptr, nullptr, nullptr, k16);
  gemm_bt<0><<<gQKV, 256, 0, stream>>>(fb16, wv16, NTOK, DMODEL, DMODEL, nullptr, nullptr, nullptr, v16);
  transpose_kernel<<<dim3(NTOK / 64, DMODEL / 64), 256, 0, stream>>>(v16, vt16);
  attn4_kernel<<<dim3(NTOK / 32 * NHEAD), 128, 0, stream>>>(q16, k16, vt16, cfl, att16);
  gemm_bt<1><<<gQKV, 256, 0, stream>>>(att16, wo16, NTOK, DMODEL, DMODEL, bo, features, acc1, nullptr);
  ln_kernel<<<dim3(NTOK), 256, 0, stream>>>(acc1, ln1g, ln1b, xf, x16);
  gemm_bt<2><<<dim3(NTOK / 128, DFFN / 128), 256, 0, stream>>>(x16, w116, NTOK, DFFN, DMODEL, b1, nullptr, nullptr, h16);
  gemm_bt<3><<<gQKV, 256, 0, stream>>>(h16, w216, NTOK, DMODEL, DFFN, b2, xf, acc1, nullptr);
  ln_kernel<<<dim3(NTOK), 256, 0, stream>>>(acc1, ln2g, ln2b, outp, nullptr);
}

// Round 6
// 509.830 us; speedup vs baseline: 4.9273x; 4.9273x over previous
//
#include <hip/hip_runtime.h>
#include <cstdint>
#include <cstddef>

#define NTOK 4096
#define DMODEL 1024
#define NHEAD 8
#define DHEAD 128
#define DFFN 1536
#define LNEPS 1e-5f

typedef __bf16 bf16_t;
typedef __bf16 bf16x8 __attribute__((ext_vector_type(8)));
typedef __bf16 bf16x4 __attribute__((ext_vector_type(4)));
typedef float f32x4 __attribute__((ext_vector_type(4)));
typedef float f32x16 __attribute__((ext_vector_type(16)));

__device__ __forceinline__ void gload_lds16(const bf16_t* g, bf16_t* lds) {
  __builtin_amdgcn_global_load_lds(
      (const __attribute__((address_space(1))) unsigned int*)g,
      (__attribute__((address_space(3))) unsigned int*)lds, 16, 0, 0);
}

__device__ __forceinline__ unsigned pkbf(float lo, float hi) {
  unsigned a = (unsigned)__builtin_bit_cast(unsigned short, (bf16_t)lo);
  unsigned b = (unsigned)__builtin_bit_cast(unsigned short, (bf16_t)hi);
  return (b << 16) | a;
}

// ---------------- f32 -> bf16 convert ----------------
__global__ __launch_bounds__(256) void cvt_kernel(const float* __restrict__ in,
                                                  bf16_t* __restrict__ out, int n4) {
  int i = blockIdx.x * 256 + threadIdx.x;
  if (i < n4) {
    const float4 v = reinterpret_cast<const float4*>(in)[i];
    bf16x4 o = {(bf16_t)v.x, (bf16_t)v.y, (bf16_t)v.z, (bf16_t)v.w};
    reinterpret_cast<bf16x4*>(out)[i] = o;
  }
}

// ---------------- int2 coords -> float2 ----------------
__global__ __launch_bounds__(256) void cvtc_kernel(const int* __restrict__ in,
                                                   float2* __restrict__ out, int n) {
  int i = blockIdx.x * 256 + threadIdx.x;
  if (i < n) {
    int2 c = reinterpret_cast<const int2*>(in)[i];
    out[i] = make_float2((float)c.x, (float)c.y);
  }
}

// ---------------- bf16 GEMM, C = A @ B^T (+ epilogue) ----------------
template<int EPI>
__global__ __launch_bounds__(256) void gemm_bt(
    const bf16_t* __restrict__ A, const bf16_t* __restrict__ B,
    int M, int Nn, int K,
    const float* __restrict__ bias, const float* __restrict__ resid,
    float* __restrict__ outF, bf16_t* __restrict__ outH)
{
  __shared__ bf16_t As[128 * 32];
  __shared__ bf16_t Bs[128 * 32];
  const int t = threadIdx.x;
  const int w = t >> 6, l = t & 63;
  const int lg = l >> 4, li = l & 15;
  const int m0 = blockIdx.x * 128, n0 = blockIdx.y * 128;
  const int wr = (w >> 1) * 64, wc = (w & 1) * 64;
  const f32x4 fz = {0.f, 0.f, 0.f, 0.f};
  f32x4 acc[4][4];
#pragma unroll
  for (int i = 0; i < 4; i++)
#pragma unroll
    for (int j = 0; j < 4; j++) acc[i][j] = fz;

  const bf16_t* Ag = A + (size_t)m0 * K;
  const bf16_t* Bg = B + (size_t)n0 * K;

  for (int kt = 0; kt < K; kt += 32) {
    if (kt) __syncthreads();
#pragma unroll
    for (int p = 0; p < 2; p++) {
      int c = p * 256 + w * 64 + l;
      gload_lds16(Ag + (size_t)(c >> 2) * K + kt + (c & 3) * 8,
                  As + (p * 256 + w * 64) * 8);
      gload_lds16(Bg + (size_t)(c >> 2) * K + kt + (c & 3) * 8,
                  Bs + (p * 256 + w * 64) * 8);
    }
    __syncthreads();
    bf16x8 af[4], bfr[4];
#pragma unroll
    for (int mi = 0; mi < 4; mi++)
      af[mi] = *reinterpret_cast<const bf16x8*>(&As[(wr + mi * 16 + li) * 32 + lg * 8]);
#pragma unroll
    for (int ni = 0; ni < 4; ni++)
      bfr[ni] = *reinterpret_cast<const bf16x8*>(&Bs[(wc + ni * 16 + li) * 32 + lg * 8]);
#pragma unroll
    for (int mi = 0; mi < 4; mi++)
#pragma unroll
      for (int ni = 0; ni < 4; ni++)
        acc[mi][ni] = __builtin_amdgcn_mfma_f32_16x16x32_bf16(af[mi], bfr[ni], acc[mi][ni], 0, 0, 0);
  }

#pragma unroll
  for (int mi = 0; mi < 4; mi++) {
#pragma unroll
    for (int ni = 0; ni < 4; ni++) {
      int gcol = n0 + wc + ni * 16 + li;
#pragma unroll
      for (int r = 0; r < 4; r++) {
        int grow = m0 + wr + mi * 16 + lg * 4 + r;
        float v = acc[mi][ni][r];
        if (EPI == 0) {
          outH[(size_t)grow * Nn + gcol] = (bf16_t)v;
        } else if (EPI == 1) {
          v += bias[gcol] + resid[(size_t)grow * Nn + gcol];
          outF[(size_t)grow * Nn + gcol] = v;
        } else if (EPI == 2) {
          v += bias[gcol];
          v = 0.5f * v * (1.f + erff(v * 0.70710678118654752f));
          outH[(size_t)grow * Nn + gcol] = (bf16_t)v;
        } else {
          v += bias[gcol] + resid[(size_t)grow * Nn + gcol];
          outF[(size_t)grow * Nn + gcol] = v;
        }
      }
    }
  }
}

// ---------------- bf16 transpose [NTOK,DMODEL] -> [DMODEL,NTOK] ----------------
__global__ __launch_bounds__(256) void transpose_kernel(const bf16_t* __restrict__ in,
                                                        bf16_t* __restrict__ out)
{
  __shared__ bf16_t tile[64][72];
  int t = threadIdx.x;
  int nb = blockIdx.x * 64, db = blockIdx.y * 64;
#pragma unroll
  for (int p = 0; p < 2; p++) {
    int c = p * 256 + t;
    int n = c >> 3, cb = c & 7;
    bf16x8 v = *reinterpret_cast<const bf16x8*>(in + (size_t)(nb + n) * DMODEL + db + cb * 8);
    *reinterpret_cast<bf16x8*>(&tile[n][cb * 8]) = v;
  }
  __syncthreads();
#pragma unroll
  for (int p = 0; p < 2; p++) {
    int c = p * 256 + t;
    int d = c >> 3, nc = (c & 7) * 8;
    bf16x8 vv;
#pragma unroll
    for (int j = 0; j < 8; j++) vv[j] = tile[nc + j][d];
    *reinterpret_cast<bf16x8*>(out + (size_t)(db + d) * NTOK + nb + nc) = vv;
  }
}

// ---------------- fused dual-softmax flash attention, v5 ----------------
// v4 structure (no-LDS main loop, swapped QK^T, shfl P-redistribution,
// 17.4KB epilogue LDS) but MAX-FREE softmax: logits are bounded
// (|s| < ~3, bias >= 0, diagonal keeps denominators > 0.007), so we skip
// online max tracking entirely: no fmax trees, no per-iter shuffles, no
// rescale branch, plain-add epilogue merge. bpp folded into coord scale.
__global__ __launch_bounds__(128, 2) void attn5_kernel(
    const bf16_t* __restrict__ Q, const bf16_t* __restrict__ K,
    const bf16_t* __restrict__ Vt, const float2* __restrict__ cf,
    bf16_t* __restrict__ out)
{
  __shared__ float buf[128 * 33];   // 16.9KB, reused in 3 epilogue passes
  __shared__ float mlS[2][32];

  const int t = threadIdx.x;
  const int w = t >> 6;
  const int l = t & 63;
  const int q5 = l & 31;
  const int hi = l >> 5;
  const int h = blockIdx.x & 7;
  const int q0 = (blockIdx.x >> 3) * 32;
  const float LOG2E = 1.44269504088896f;
  const float isq = 0.08838834764831845f;   // 1/sqrt(128)
  const float itau = 1.6666666666666667f;   // 1/0.6
  const float hs = 1.0f / (float)(2 << h);
  const float ap = isq * LOG2E;             // score scale, pos (log2 units)
  const float an = -isq * itau * LOG2E;     // score scale, neg
  const float bpp = hs * LOG2E;             // bias scale, pos (neg = *itau)

  // preload Q fragments (B-operand: col q = lane&31, k = d = 16c + 8hi + j)
  bf16x8 qf[8];
  {
    const bf16_t* qrow = Q + (size_t)(q0 + q5) * DMODEL + h * DHEAD;
#pragma unroll
    for (int c = 0; c < 8; c++)
      qf[c] = *reinterpret_cast<const bf16x8*>(qrow + c * 16 + hi * 8);
  }
  const float2 qc = cf[q0 + q5];
  const float qxs = qc.x * bpp, qys = qc.y * bpp;

  f32x16 accp[4], accn[4];
#pragma unroll
  for (int f = 0; f < 4; f++) {
#pragma unroll
    for (int r = 0; r < 16; r++) { accp[f][r] = 0.f; accn[f][r] = 0.f; }
  }
  float lp = 0.f, lN = 0.f;   // per-lane partial sums (reduced at end)

  const bf16_t* krow = K + (size_t)(w * 2048 + q5) * DMODEL + h * DHEAD + hi * 8;
  const bf16_t* vrow0 = Vt + (size_t)(h * DHEAD + q5) * NTOK + w * 2048 + hi * 8;

  for (int it = 0; it < 64; it++) {
    const int kv0 = w * 2048 + it * 32;

    // ---- issue K-frag loads (direct global; row kv0+q5) ----
    bf16x8 kf[8];
    {
      const bf16_t* kp = krow + (size_t)it * 32 * DMODEL;
#pragma unroll
      for (int c = 0; c < 8; c++)
        kf[c] = *reinterpret_cast<const bf16x8*>(kp + c * 16);
    }

    // ---- S^T = K * Q^T (32 kv x 32 q) ----
    f32x16 sacc;
#pragma unroll
    for (int r = 0; r < 16; r++) sacc[r] = 0.f;
#pragma unroll
    for (int c = 0; c < 8; c++)
      sacc = __builtin_amdgcn_mfma_f32_32x32x16_bf16(kf[c], qf[c], sacc, 0, 0, 0);

    // ---- issue V-frag loads (consumed after softmax; latency hidden) ----
    bf16x8 vf[8];
#pragma unroll
    for (int ks = 0; ks < 2; ks++)
#pragma unroll
      for (int f = 0; f < 4; f++)
        vf[ks * 4 + f] = *reinterpret_cast<const bf16x8*>(
            vrow0 + (size_t)(32 * f) * NTOK + it * 32 + ks * 16);

    // ---- max-free dual softmax (log2 domain) ----
    float p16[16], n16[16];
#pragma unroll
    for (int r = 0; r < 16; r++) {
      int kvr = kv0 + (r & 3) + 8 * (r >> 2) + 4 * hi;
      float2 c = cf[kvr];
      float dx = __builtin_fmaf(c.x, -bpp, qxs);
      float dy = __builtin_fmaf(c.y, -bpp, qys);
      float u = sqrtf(__builtin_fmaf(dy, dy, dx * dx));  // dist*hs*log2e
      float pv = exp2f(__builtin_fmaf(sacc[r], ap, -u));
      float nv = exp2f(__builtin_fmaf(sacc[r], an, -u * itau));
      p16[r] = pv; n16[r] = nv;
      lp += pv; lN += nv;
    }

    // ---- pack P^T to bf16 B-frags, redistribute via shfl_xor(32) ----
    unsigned pw[2][4], nw[2][4];
#pragma unroll
    for (int ks = 0; ks < 2; ks++) {
#pragma unroll
      for (int u = 0; u < 2; u++) {
        unsigned A = pkbf(p16[8 * ks + 2 * u], p16[8 * ks + 2 * u + 1]);
        unsigned B = pkbf(p16[8 * ks + 4 + 2 * u], p16[8 * ks + 4 + 2 * u + 1]);
        unsigned Ax = __shfl_xor(A, 32, 64);
        unsigned Bx = __shfl_xor(B, 32, 64);
        pw[ks][u] = hi ? Bx : A;
        pw[ks][2 + u] = hi ? B : Ax;
        unsigned C = pkbf(n16[8 * ks + 2 * u], n16[8 * ks + 2 * u + 1]);
        unsigned D = pkbf(n16[8 * ks + 4 + 2 * u], n16[8 * ks + 4 + 2 * u + 1]);
        unsigned Cx = __shfl_xor(C, 32, 64);
        unsigned Dx = __shfl_xor(D, 32, 64);
        nw[ks][u] = hi ? Dx : C;
        nw[ks][2 + u] = hi ? D : Cx;
      }
    }

    // ---- PV: O^T += V^T * P^T ----
#pragma unroll
    for (int ks = 0; ks < 2; ks++) {
      union { unsigned u[4]; bf16x8 v; } pb, nb;
#pragma unroll
      for (int j = 0; j < 4; j++) { pb.u[j] = pw[ks][j]; nb.u[j] = nw[ks][j]; }
#pragma unroll
      for (int f = 0; f < 4; f++) {
        accp[f] = __builtin_amdgcn_mfma_f32_32x32x16_bf16(vf[ks * 4 + f], pb.v, accp[f], 0, 0, 0);
        accn[f] = __builtin_amdgcn_mfma_f32_32x32x16_bf16(vf[ks * 4 + f], nb.v, accn[f], 0, 0, 0);
      }
    }
  }

  // ---- reduce l across the two lane-halves (kv rows split by hi) ----
  float lpw = lp + __shfl_xor(lp, 32, 64);
  float lnw = lN + __shfl_xor(lN, 32, 64);

  // ---- cross-wave combine: plain adds (no max merging needed) ----
  __syncthreads();
  if (w == 1) {
    if (l == 0) { mlS[0][q5] = 0.f; }   // dummy to keep mlS live
    if (hi == 0) { mlS[0][q5] = lpw; mlS[1][q5] = lnw; }
#pragma unroll
    for (int f = 0; f < 4; f++)
#pragma unroll
      for (int r = 0; r < 16; r++)
        buf[(32 * f + (r & 3) + 8 * (r >> 2) + 4 * hi) * 33 + q5] = accp[f][r];
  }
  __syncthreads();
  float lpt = 0.f, lnt = 0.f;
  if (w == 0) {
    lpt = lpw + mlS[0][q5];
    lnt = lnw + mlS[1][q5];
#pragma unroll
    for (int f = 0; f < 4; f++)
#pragma unroll
      for (int r = 0; r < 16; r++)
        accp[f][r] += buf[(32 * f + (r & 3) + 8 * (r >> 2) + 4 * hi) * 33 + q5];
  }
  __syncthreads();
  if (w == 1) {
#pragma unroll
    for (int f = 0; f < 4; f++)
#pragma unroll
      for (int r = 0; r < 16; r++)
        buf[(32 * f + (r & 3) + 8 * (r >> 2) + 4 * hi) * 33 + q5] = accn[f][r];
  }
  __syncthreads();
  if (w == 0) {
    float ip = 1.f / lpt, inn = 1.5f / lnt;
#pragma unroll
    for (int f = 0; f < 4; f++)
#pragma unroll
      for (int r = 0; r < 16; r++) {
        int row = 32 * f + (r & 3) + 8 * (r >> 2) + 4 * hi;
        float an2 = accn[f][r] + buf[row * 33 + q5];
        buf[row * 33 + q5] = accp[f][r] * ip - an2 * inn;
      }
  }
  __syncthreads();

  // ---- transpose store: thread t -> q = t>>2, d-quarter = (t&3)*32 ----
  {
    int q = t >> 2, dq = (t & 3) * 32;
#pragma unroll
    for (int j = 0; j < 4; j++) {
      bf16x8 ov;
#pragma unroll
      for (int e = 0; e < 8; e++) ov[e] = (bf16_t)buf[(dq + j * 8 + e) * 33 + q];
      *reinterpret_cast<bf16x8*>(out + (size_t)(q0 + q) * DMODEL + h * DHEAD + dq + j * 8) = ov;
    }
  }
}

// ---------------- row LayerNorm (D=1024) ----------------
__global__ __launch_bounds__(256) void ln_kernel(
    const float* __restrict__ in, const float* __restrict__ g, const float* __restrict__ b,
    float* __restrict__ outF, bf16_t* __restrict__ outH)
{
  int row = blockIdx.x, t = threadIdx.x;
  const float4 v = reinterpret_cast<const float4*>(in + (size_t)row * DMODEL)[t];
  float s = v.x + v.y + v.z + v.w;
  float ss = v.x * v.x + v.y * v.y + v.z * v.z + v.w * v.w;
#pragma unroll
  for (int m = 32; m >= 1; m >>= 1) {
    s += __shfl_xor(s, m, 64);
    ss += __shfl_xor(ss, m, 64);
  }
  __shared__ float red[8];
  int w = t >> 6, l = t & 63;
  if (l == 0) { red[w] = s; red[4 + w] = ss; }
  __syncthreads();
  s = red[0] + red[1] + red[2] + red[3];
  ss = red[4] + red[5] + red[6] + red[7];
  float mu = s * (1.f / DMODEL);
  float var = ss * (1.f / DMODEL) - mu * mu;
  float rs = rsqrtf(var + LNEPS);
  const float4 gv = reinterpret_cast<const float4*>(g)[t];
  const float4 bv = reinterpret_cast<const float4*>(b)[t];
  float y0 = (v.x - mu) * rs * gv.x + bv.x;
  float y1 = (v.y - mu) * rs * gv.y + bv.y;
  float y2 = (v.z - mu) * rs * gv.z + bv.z;
  float y3 = (v.w - mu) * rs * gv.w + bv.w;
  if (outF) {
    float4 o; o.x = y0; o.y = y1; o.z = y2; o.w = y3;
    reinterpret_cast<float4*>(outF + (size_t)row * DMODEL)[t] = o;
  }
  if (outH) {
    bf16x4 o = {(bf16_t)y0, (bf16_t)y1, (bf16_t)y2, (bf16_t)y3};
    reinterpret_cast<bf16x4*>(outH + (size_t)row * DMODEL)[t] = o;
  }
}

extern "C" void kernel_launch(void* const* d_in, const int* in_sizes, int n_in,
                              void* d_out, int out_size, void* d_ws, size_t ws_size,
                              hipStream_t stream) {
  (void)in_sizes; (void)n_in; (void)out_size; (void)ws_size;
  const float* features = (const float*)d_in[0];
  const int* coords = (const int*)d_in[1];
  const float* Wq = (const float*)d_in[2];
  const float* Wk = (const float*)d_in[3];
  const float* Wv = (const float*)d_in[4];
  const float* Wo = (const float*)d_in[5];
  const float* bo = (const float*)d_in[6];
  const float* ln1g = (const float*)d_in[7];
  const float* ln1b = (const float*)d_in[8];
  const float* W1 = (const float*)d_in[9];
  const float* b1 = (const float*)d_in[10];
  const float* W2 = (const float*)d_in[11];
  const float* b2 = (const float*)d_in[12];
  const float* ln2g = (const float*)d_in[13];
  const float* ln2b = (const float*)d_in[14];
  float* outp = (float*)d_out;

  char* ws = (char*)d_ws;
  size_t off = 0;
  auto alloc = [&](size_t bytes) -> void* {
    void* p = ws + off;
    off += (bytes + 255) & ~((size_t)255);
    return p;
  };
  bf16_t* fb16 = (bf16_t*)alloc((size_t)NTOK * DMODEL * 2);
  bf16_t* wq16 = (bf16_t*)alloc((size_t)DMODEL * DMODEL * 2);
  bf16_t* wk16 = (bf16_t*)alloc((size_t)DMODEL * DMODEL * 2);
  bf16_t* wv16 = (bf16_t*)alloc((size_t)DMODEL * DMODEL * 2);
  bf16_t* wo16 = (bf16_t*)alloc((size_t)DMODEL * DMODEL * 2);
  bf16_t* w116 = (bf16_t*)alloc((size_t)DFFN * DMODEL * 2);
  bf16_t* w216 = (bf16_t*)alloc((size_t)DMODEL * DFFN * 2);
  bf16_t* q16 = (bf16_t*)alloc((size_t)NTOK * DMODEL * 2);
  bf16_t* k16 = (bf16_t*)alloc((size_t)NTOK * DMODEL * 2);
  bf16_t* v16 = (bf16_t*)alloc((size_t)NTOK * DMODEL * 2);
  bf16_t* vt16 = (bf16_t*)alloc((size_t)NTOK * DMODEL * 2);
  float* acc1 = (float*)alloc((size_t)NTOK * DMODEL * 4);
  float* xf = (float*)alloc((size_t)NTOK * DMODEL * 4);
  bf16_t* x16 = (bf16_t*)alloc((size_t)NTOK * DMODEL * 2);
  bf16_t* h16 = (bf16_t*)alloc((size_t)NTOK * DFFN * 2);
  float2* cfl = (float2*)alloc((size_t)NTOK * sizeof(float2));
  bf16_t* att16 = fb16;

  cvt_kernel<<<dim3(NTOK * DMODEL / 1024), 256, 0, stream>>>(features, fb16, NTOK * DMODEL / 4);
  cvt_kernel<<<dim3(DMODEL * DMODEL / 1024), 256, 0, stream>>>(Wq, wq16, DMODEL * DMODEL / 4);
  cvt_kernel<<<dim3(DMODEL * DMODEL / 1024), 256, 0, stream>>>(Wk, wk16, DMODEL * DMODEL / 4);
  cvt_kernel<<<dim3(DMODEL * DMODEL / 1024), 256, 0, stream>>>(Wv, wv16, DMODEL * DMODEL / 4);
  cvt_kernel<<<dim3(DMODEL * DMODEL / 1024), 256, 0, stream>>>(Wo, wo16, DMODEL * DMODEL / 4);
  cvt_kernel<<<dim3(DFFN * DMODEL / 1024), 256, 0, stream>>>(W1, w116, DFFN * DMODEL / 4);
  cvt_kernel<<<dim3(DMODEL * DFFN / 1024), 256, 0, stream>>>(W2, w216, DMODEL * DFFN / 4);
  cvtc_kernel<<<dim3(NTOK / 256), 256, 0, stream>>>(coords, cfl, NTOK);

  dim3 gQKV(NTOK / 128, DMODEL / 128);
  gemm_bt<0><<<gQKV, 256, 0, stream>>>(fb16, wq16, NTOK, DMODEL, DMODEL, nullptr, nullptr, nullptr, q16);
  gemm_bt<0><<<gQKV, 256, 0, stream>>>(fb16, wk16, NTOK, DMODEL, DMODEL, nullptr, nullptr, nullptr, k16);
  gemm_bt<0><<<gQKV, 256, 0, stream>>>(fb16, wv16, NTOK, DMODEL, DMODEL, nullptr, nullptr, nullptr, v16);
  transpose_kernel<<<dim3(NTOK / 64, DMODEL / 64), 256, 0, stream>>>(v16, vt16);
  attn5_kernel<<<dim3(NTOK / 32 * NHEAD), 128, 0, stream>>>(q16, k16, vt16, cfl, att16);
  gemm_bt<1><<<gQKV, 256, 0, stream>>>(att16, wo16, NTOK, DMODEL, DMODEL, bo, features, acc1, nullptr);
  ln_kernel<<<dim3(NTOK), 256, 0, stream>>>(acc1, ln1g, ln1b, xf, x16);
  gemm_bt<2><<<dim3(NTOK / 128, DFFN / 128), 256, 0, stream>>>(x16, w116, NTOK, DFFN, DMODEL, b1, nullptr, nullptr, h16);
  gemm_bt<3><<<gQKV, 256, 0, stream>>>(h16, w216, NTOK, DMODEL, DFFN, b2, xf, acc1, nullptr);
  ln_kernel<<<dim3(NTOK), 256, 0, stream>>>(acc1, ln2g, ln2b, outp, nullptr);
}

// Round 7
// 488.705 us; speedup vs baseline: 5.1403x; 1.0432x over previous
//
#include <hip/hip_runtime.h>
#include <cstdint>
#include <cstddef>

#define NTOK 4096
#define DMODEL 1024
#define NHEAD 8
#define DHEAD 128
#define DFFN 1536
#define LNEPS 1e-5f

typedef __bf16 bf16_t;
typedef __bf16 bf16x8 __attribute__((ext_vector_type(8)));
typedef __bf16 bf16x4 __attribute__((ext_vector_type(4)));
typedef float f32x4 __attribute__((ext_vector_type(4)));
typedef float f32x16 __attribute__((ext_vector_type(16)));

__device__ __forceinline__ void gload_lds16(const bf16_t* g, bf16_t* lds) {
  __builtin_amdgcn_global_load_lds(
      (const __attribute__((address_space(1))) unsigned int*)g,
      (__attribute__((address_space(3))) unsigned int*)lds, 16, 0, 0);
}

// raw-ISA math (single instruction each; ~1ulp, fine for bf16 outputs)
__device__ __forceinline__ float fexp2(float x) {
  float r;
  asm("v_exp_f32 %0, %1" : "=v"(r) : "v"(x));
  return r;
}
__device__ __forceinline__ float fsqrt(float x) {
  float r;
  asm("v_sqrt_f32 %0, %1" : "=v"(r) : "v"(x));
  return r;
}
__device__ __forceinline__ unsigned cvtpk(float lo, float hi) {
  unsigned r;
  asm("v_cvt_pk_bf16_f32 %0, %1, %2" : "=v"(r) : "v"(lo), "v"(hi));
  return r;
}

// ---------------- f32 -> bf16 convert ----------------
__global__ __launch_bounds__(256) void cvt_kernel(const float* __restrict__ in,
                                                  bf16_t* __restrict__ out, int n4) {
  int i = blockIdx.x * 256 + threadIdx.x;
  if (i < n4) {
    const float4 v = reinterpret_cast<const float4*>(in)[i];
    bf16x4 o = {(bf16_t)v.x, (bf16_t)v.y, (bf16_t)v.z, (bf16_t)v.w};
    reinterpret_cast<bf16x4*>(out)[i] = o;
  }
}

// ---------------- int2 coords -> float2 ----------------
__global__ __launch_bounds__(256) void cvtc_kernel(const int* __restrict__ in,
                                                   float2* __restrict__ out, int n) {
  int i = blockIdx.x * 256 + threadIdx.x;
  if (i < n) {
    int2 c = reinterpret_cast<const int2*>(in)[i];
    out[i] = make_float2((float)c.x, (float)c.y);
  }
}

// ---------------- bf16 GEMM, C = A @ B^T (+ epilogue) ----------------
template<int EPI>
__global__ __launch_bounds__(256) void gemm_bt(
    const bf16_t* __restrict__ A, const bf16_t* __restrict__ B,
    int M, int Nn, int K,
    const float* __restrict__ bias, const float* __restrict__ resid,
    float* __restrict__ outF, bf16_t* __restrict__ outH)
{
  __shared__ bf16_t As[128 * 32];
  __shared__ bf16_t Bs[128 * 32];
  const int t = threadIdx.x;
  const int w = t >> 6, l = t & 63;
  const int lg = l >> 4, li = l & 15;
  const int m0 = blockIdx.x * 128, n0 = blockIdx.y * 128;
  const int wr = (w >> 1) * 64, wc = (w & 1) * 64;
  const f32x4 fz = {0.f, 0.f, 0.f, 0.f};
  f32x4 acc[4][4];
#pragma unroll
  for (int i = 0; i < 4; i++)
#pragma unroll
    for (int j = 0; j < 4; j++) acc[i][j] = fz;

  const bf16_t* Ag = A + (size_t)m0 * K;
  const bf16_t* Bg = B + (size_t)n0 * K;

  for (int kt = 0; kt < K; kt += 32) {
    if (kt) __syncthreads();
#pragma unroll
    for (int p = 0; p < 2; p++) {
      int c = p * 256 + w * 64 + l;
      gload_lds16(Ag + (size_t)(c >> 2) * K + kt + (c & 3) * 8,
                  As + (p * 256 + w * 64) * 8);
      gload_lds16(Bg + (size_t)(c >> 2) * K + kt + (c & 3) * 8,
                  Bs + (p * 256 + w * 64) * 8);
    }
    __syncthreads();
    bf16x8 af[4], bfr[4];
#pragma unroll
    for (int mi = 0; mi < 4; mi++)
      af[mi] = *reinterpret_cast<const bf16x8*>(&As[(wr + mi * 16 + li) * 32 + lg * 8]);
#pragma unroll
    for (int ni = 0; ni < 4; ni++)
      bfr[ni] = *reinterpret_cast<const bf16x8*>(&Bs[(wc + ni * 16 + li) * 32 + lg * 8]);
#pragma unroll
    for (int mi = 0; mi < 4; mi++)
#pragma unroll
      for (int ni = 0; ni < 4; ni++)
        acc[mi][ni] = __builtin_amdgcn_mfma_f32_16x16x32_bf16(af[mi], bfr[ni], acc[mi][ni], 0, 0, 0);
  }

#pragma unroll
  for (int mi = 0; mi < 4; mi++) {
#pragma unroll
    for (int ni = 0; ni < 4; ni++) {
      int gcol = n0 + wc + ni * 16 + li;
#pragma unroll
      for (int r = 0; r < 4; r++) {
        int grow = m0 + wr + mi * 16 + lg * 4 + r;
        float v = acc[mi][ni][r];
        if (EPI == 0) {
          outH[(size_t)grow * Nn + gcol] = (bf16_t)v;
        } else if (EPI == 1) {
          v += bias[gcol] + resid[(size_t)grow * Nn + gcol];
          outF[(size_t)grow * Nn + gcol] = v;
        } else if (EPI == 2) {
          v += bias[gcol];
          v = 0.5f * v * (1.f + erff(v * 0.70710678118654752f));
          outH[(size_t)grow * Nn + gcol] = (bf16_t)v;
        } else {
          v += bias[gcol] + resid[(size_t)grow * Nn + gcol];
          outF[(size_t)grow * Nn + gcol] = v;
        }
      }
    }
  }
}

// ---------------- bf16 transpose [NTOK,DMODEL] -> [DMODEL,NTOK] ----------------
__global__ __launch_bounds__(256) void transpose_kernel(const bf16_t* __restrict__ in,
                                                        bf16_t* __restrict__ out)
{
  __shared__ bf16_t tile[64][72];
  int t = threadIdx.x;
  int nb = blockIdx.x * 64, db = blockIdx.y * 64;
#pragma unroll
  for (int p = 0; p < 2; p++) {
    int c = p * 256 + t;
    int n = c >> 3, cb = c & 7;
    bf16x8 v = *reinterpret_cast<const bf16x8*>(in + (size_t)(nb + n) * DMODEL + db + cb * 8);
    *reinterpret_cast<bf16x8*>(&tile[n][cb * 8]) = v;
  }
  __syncthreads();
#pragma unroll
  for (int p = 0; p < 2; p++) {
    int c = p * 256 + t;
    int d = c >> 3, nc = (c & 7) * 8;
    bf16x8 vv;
#pragma unroll
    for (int j = 0; j < 8; j++) vv[j] = tile[nc + j][d];
    *reinterpret_cast<bf16x8*>(out + (size_t)(db + d) * NTOK + nb + nc) = vv;
  }
}

// ---------------- fused dual-softmax flash attention, v6 ----------------
// v5 (max-free, no-LDS main loop) + raw-ISA math: v_sqrt_f32 / v_exp_f32 /
// v_cvt_pk_bf16_f32 single-instruction forms (libm lowering was ~5x the
// static instruction count), and QK^T split into two 4-deep MFMA chains
// to halve exposed MFMA latency.
__global__ __launch_bounds__(128, 2) void attn6_kernel(
    const bf16_t* __restrict__ Q, const bf16_t* __restrict__ K,
    const bf16_t* __restrict__ Vt, const float2* __restrict__ cf,
    bf16_t* __restrict__ out)
{
  __shared__ float buf[128 * 33];   // 16.9KB, reused in 3 epilogue passes
  __shared__ float mlS[2][32];

  const int t = threadIdx.x;
  const int w = t >> 6;
  const int l = t & 63;
  const int q5 = l & 31;
  const int hi = l >> 5;
  const int h = blockIdx.x & 7;
  const int q0 = (blockIdx.x >> 3) * 32;
  const float LOG2E = 1.44269504088896f;
  const float isq = 0.08838834764831845f;   // 1/sqrt(128)
  const float itau = 1.6666666666666667f;   // 1/0.6
  const float hs = 1.0f / (float)(2 << h);
  const float ap = isq * LOG2E;             // score scale, pos (log2 units)
  const float an = -isq * itau * LOG2E;     // score scale, neg
  const float bpp = hs * LOG2E;             // bias scale, pos (neg = *itau)

  // preload Q fragments (B-operand: col q = lane&31, k = d = 16c + 8hi + j)
  bf16x8 qf[8];
  {
    const bf16_t* qrow = Q + (size_t)(q0 + q5) * DMODEL + h * DHEAD;
#pragma unroll
    for (int c = 0; c < 8; c++)
      qf[c] = *reinterpret_cast<const bf16x8*>(qrow + c * 16 + hi * 8);
  }
  const float2 qc = cf[q0 + q5];
  const float qxs = qc.x * bpp, qys = qc.y * bpp;

  f32x16 accp[4], accn[4];
#pragma unroll
  for (int f = 0; f < 4; f++) {
#pragma unroll
    for (int r = 0; r < 16; r++) { accp[f][r] = 0.f; accn[f][r] = 0.f; }
  }
  float lp = 0.f, lN = 0.f;   // per-lane partial sums (reduced at end)

  const bf16_t* krow = K + (size_t)(w * 2048 + q5) * DMODEL + h * DHEAD + hi * 8;
  const bf16_t* vrow0 = Vt + (size_t)(h * DHEAD + q5) * NTOK + w * 2048 + hi * 8;

  for (int it = 0; it < 64; it++) {
    const int kv0 = w * 2048 + it * 32;

    // ---- issue K-frag loads (direct global; row kv0+q5) ----
    bf16x8 kf[8];
    {
      const bf16_t* kp = krow + (size_t)it * 32 * DMODEL;
#pragma unroll
      for (int c = 0; c < 8; c++)
        kf[c] = *reinterpret_cast<const bf16x8*>(kp + c * 16);
    }

    // ---- S^T = K * Q^T (32 kv x 32 q), two parallel 4-deep chains ----
    f32x16 sacc, sacc2;
#pragma unroll
    for (int r = 0; r < 16; r++) { sacc[r] = 0.f; sacc2[r] = 0.f; }
#pragma unroll
    for (int c = 0; c < 4; c++) {
      sacc = __builtin_amdgcn_mfma_f32_32x32x16_bf16(kf[2 * c], qf[2 * c], sacc, 0, 0, 0);
      sacc2 = __builtin_amdgcn_mfma_f32_32x32x16_bf16(kf[2 * c + 1], qf[2 * c + 1], sacc2, 0, 0, 0);
    }
#pragma unroll
    for (int r = 0; r < 16; r++) sacc[r] += sacc2[r];

    // ---- issue V-frag loads (consumed after softmax; latency hidden) ----
    bf16x8 vf[8];
#pragma unroll
    for (int ks = 0; ks < 2; ks++)
#pragma unroll
      for (int f = 0; f < 4; f++)
        vf[ks * 4 + f] = *reinterpret_cast<const bf16x8*>(
            vrow0 + (size_t)(32 * f) * NTOK + it * 32 + ks * 16);

    // ---- max-free dual softmax (log2 domain), raw-ISA math ----
    float p16[16], n16[16];
#pragma unroll
    for (int r = 0; r < 16; r++) {
      int kvr = kv0 + (r & 3) + 8 * (r >> 2) + 4 * hi;
      float2 c = cf[kvr];
      float dx = __builtin_fmaf(c.x, -bpp, qxs);
      float dy = __builtin_fmaf(c.y, -bpp, qys);
      float u = fsqrt(__builtin_fmaf(dy, dy, dx * dx));  // dist*hs*log2e
      float pv = fexp2(__builtin_fmaf(sacc[r], ap, -u));
      float nv = fexp2(__builtin_fmaf(sacc[r], an, u * -itau));
      p16[r] = pv; n16[r] = nv;
      lp += pv; lN += nv;
    }

    // ---- pack P^T to bf16 B-frags, redistribute via shfl_xor(32) ----
    unsigned pw[2][4], nw[2][4];
#pragma unroll
    for (int ks = 0; ks < 2; ks++) {
#pragma unroll
      for (int u = 0; u < 2; u++) {
        unsigned A = cvtpk(p16[8 * ks + 2 * u], p16[8 * ks + 2 * u + 1]);
        unsigned B = cvtpk(p16[8 * ks + 4 + 2 * u], p16[8 * ks + 4 + 2 * u + 1]);
        unsigned Ax = __shfl_xor(A, 32, 64);
        unsigned Bx = __shfl_xor(B, 32, 64);
        pw[ks][u] = hi ? Bx : A;
        pw[ks][2 + u] = hi ? B : Ax;
        unsigned C = cvtpk(n16[8 * ks + 2 * u], n16[8 * ks + 2 * u + 1]);
        unsigned D = cvtpk(n16[8 * ks + 4 + 2 * u], n16[8 * ks + 4 + 2 * u + 1]);
        unsigned Cx = __shfl_xor(C, 32, 64);
        unsigned Dx = __shfl_xor(D, 32, 64);
        nw[ks][u] = hi ? Dx : C;
        nw[ks][2 + u] = hi ? D : Cx;
      }
    }

    // ---- PV: O^T += V^T * P^T ----
#pragma unroll
    for (int ks = 0; ks < 2; ks++) {
      union { unsigned u[4]; bf16x8 v; } pb, nb;
#pragma unroll
      for (int j = 0; j < 4; j++) { pb.u[j] = pw[ks][j]; nb.u[j] = nw[ks][j]; }
#pragma unroll
      for (int f = 0; f < 4; f++) {
        accp[f] = __builtin_amdgcn_mfma_f32_32x32x16_bf16(vf[ks * 4 + f], pb.v, accp[f], 0, 0, 0);
        accn[f] = __builtin_amdgcn_mfma_f32_32x32x16_bf16(vf[ks * 4 + f], nb.v, accn[f], 0, 0, 0);
      }
    }
  }

  // ---- reduce l across the two lane-halves (kv rows split by hi) ----
  float lpw = lp + __shfl_xor(lp, 32, 64);
  float lnw = lN + __shfl_xor(lN, 32, 64);

  // ---- cross-wave combine: plain adds (no max merging needed) ----
  __syncthreads();
  if (w == 1) {
    if (hi == 0) { mlS[0][q5] = lpw; mlS[1][q5] = lnw; }
#pragma unroll
    for (int f = 0; f < 4; f++)
#pragma unroll
      for (int r = 0; r < 16; r++)
        buf[(32 * f + (r & 3) + 8 * (r >> 2) + 4 * hi) * 33 + q5] = accp[f][r];
  }
  __syncthreads();
  float lpt = 0.f, lnt = 0.f;
  if (w == 0) {
    lpt = lpw + mlS[0][q5];
    lnt = lnw + mlS[1][q5];
#pragma unroll
    for (int f = 0; f < 4; f++)
#pragma unroll
      for (int r = 0; r < 16; r++)
        accp[f][r] += buf[(32 * f + (r & 3) + 8 * (r >> 2) + 4 * hi) * 33 + q5];
  }
  __syncthreads();
  if (w == 1) {
#pragma unroll
    for (int f = 0; f < 4; f++)
#pragma unroll
      for (int r = 0; r < 16; r++)
        buf[(32 * f + (r & 3) + 8 * (r >> 2) + 4 * hi) * 33 + q5] = accn[f][r];
  }
  __syncthreads();
  if (w == 0) {
    float ip = 1.f / lpt, inn = 1.5f / lnt;
#pragma unroll
    for (int f = 0; f < 4; f++)
#pragma unroll
      for (int r = 0; r < 16; r++) {
        int row = 32 * f + (r & 3) + 8 * (r >> 2) + 4 * hi;
        float an2 = accn[f][r] + buf[row * 33 + q5];
        buf[row * 33 + q5] = accp[f][r] * ip - an2 * inn;
      }
  }
  __syncthreads();

  // ---- transpose store: thread t -> q = t>>2, d-quarter = (t&3)*32 ----
  {
    int q = t >> 2, dq = (t & 3) * 32;
#pragma unroll
    for (int j = 0; j < 4; j++) {
      bf16x8 ov;
#pragma unroll
      for (int e = 0; e < 8; e++) ov[e] = (bf16_t)buf[(dq + j * 8 + e) * 33 + q];
      *reinterpret_cast<bf16x8*>(out + (size_t)(q0 + q) * DMODEL + h * DHEAD + dq + j * 8) = ov;
    }
  }
}

// ---------------- row LayerNorm (D=1024) ----------------
__global__ __launch_bounds__(256) void ln_kernel(
    const float* __restrict__ in, const float* __restrict__ g, const float* __restrict__ b,
    float* __restrict__ outF, bf16_t* __restrict__ outH)
{
  int row = blockIdx.x, t = threadIdx.x;
  const float4 v = reinterpret_cast<const float4*>(in + (size_t)row * DMODEL)[t];
  float s = v.x + v.y + v.z + v.w;
  float ss = v.x * v.x + v.y * v.y + v.z * v.z + v.w * v.w;
#pragma unroll
  for (int m = 32; m >= 1; m >>= 1) {
    s += __shfl_xor(s, m, 64);
    ss += __shfl_xor(ss, m, 64);
  }
  __shared__ float red[8];
  int w = t >> 6, l = t & 63;
  if (l == 0) { red[w] = s; red[4 + w] = ss; }
  __syncthreads();
  s = red[0] + red[1] + red[2] + red[3];
  ss = red[4] + red[5] + red[6] + red[7];
  float mu = s * (1.f / DMODEL);
  float var = ss * (1.f / DMODEL) - mu * mu;
  float rs = rsqrtf(var + LNEPS);
  const float4 gv = reinterpret_cast<const float4*>(g)[t];
  const float4 bv = reinterpret_cast<const float4*>(b)[t];
  float y0 = (v.x - mu) * rs * gv.x + bv.x;
  float y1 = (v.y - mu) * rs * gv.y + bv.y;
  float y2 = (v.z - mu) * rs * gv.z + bv.z;
  float y3 = (v.w - mu) * rs * gv.w + bv.w;
  if (outF) {
    float4 o; o.x = y0; o.y = y1; o.z = y2; o.w = y3;
    reinterpret_cast<float4*>(outF + (size_t)row * DMODEL)[t] = o;
  }
  if (outH) {
    bf16x4 o = {(bf16_t)y0, (bf16_t)y1, (bf16_t)y2, (bf16_t)y3};
    reinterpret_cast<bf16x4*>(outH + (size_t)row * DMODEL)[t] = o;
  }
}

extern "C" void kernel_launch(void* const* d_in, const int* in_sizes, int n_in,
                              void* d_out, int out_size, void* d_ws, size_t ws_size,
                              hipStream_t stream) {
  (void)in_sizes; (void)n_in; (void)out_size; (void)ws_size;
  const float* features = (const float*)d_in[0];
  const int* coords = (const int*)d_in[1];
  const float* Wq = (const float*)d_in[2];
  const float* Wk = (const float*)d_in[3];
  const float* Wv = (const float*)d_in[4];
  const float* Wo = (const float*)d_in[5];
  const float* bo = (const float*)d_in[6];
  const float* ln1g = (const float*)d_in[7];
  const float* ln1b = (const float*)d_in[8];
  const float* W1 = (const float*)d_in[9];
  const float* b1 = (const float*)d_in[10];
  const float* W2 = (const float*)d_in[11];
  const float* b2 = (const float*)d_in[12];
  const float* ln2g = (const float*)d_in[13];
  const float* ln2b = (const float*)d_in[14];
  float* outp = (float*)d_out;

  char* ws = (char*)d_ws;
  size_t off = 0;
  auto alloc = [&](size_t bytes) -> void* {
    void* p = ws + off;
    off += (bytes + 255) & ~((size_t)255);
    return p;
  };
  bf16_t* fb16 = (bf16_t*)alloc((size_t)NTOK * DMODEL * 2);
  bf16_t* wq16 = (bf16_t*)alloc((size_t)DMODEL * DMODEL * 2);
  bf16_t* wk16 = (bf16_t*)alloc((size_t)DMODEL * DMODEL * 2);
  bf16_t* wv16 = (bf16_t*)alloc((size_t)DMODEL * DMODEL * 2);
  bf16_t* wo16 = (bf16_t*)alloc((size_t)DMODEL * DMODEL * 2);
  bf16_t* w116 = (bf16_t*)alloc((size_t)DFFN * DMODEL * 2);
  bf16_t* w216 = (bf16_t*)alloc((size_t)DMODEL * DFFN * 2);
  bf16_t* q16 = (bf16_t*)alloc((size_t)NTOK * DMODEL * 2);
  bf16_t* k16 = (bf16_t*)alloc((size_t)NTOK * DMODEL * 2);
  bf16_t* v16 = (bf16_t*)alloc((size_t)NTOK * DMODEL * 2);
  bf16_t* vt16 = (bf16_t*)alloc((size_t)NTOK * DMODEL * 2);
  float* acc1 = (float*)alloc((size_t)NTOK * DMODEL * 4);
  float* xf = (float*)alloc((size_t)NTOK * DMODEL * 4);
  bf16_t* x16 = (bf16_t*)alloc((size_t)NTOK * DMODEL * 2);
  bf16_t* h16 = (bf16_t*)alloc((size_t)NTOK * DFFN * 2);
  float2* cfl = (float2*)alloc((size_t)NTOK * sizeof(float2));
  bf16_t* att16 = fb16;

  cvt_kernel<<<dim3(NTOK * DMODEL / 1024), 256, 0, stream>>>(features, fb16, NTOK * DMODEL / 4);
  cvt_kernel<<<dim3(DMODEL * DMODEL / 1024), 256, 0, stream>>>(Wq, wq16, DMODEL * DMODEL / 4);
  cvt_kernel<<<dim3(DMODEL * DMODEL / 1024), 256, 0, stream>>>(Wk, wk16, DMODEL * DMODEL / 4);
  cvt_kernel<<<dim3(DMODEL * DMODEL / 1024), 256, 0, stream>>>(Wv, wv16, DMODEL * DMODEL / 4);
  cvt_kernel<<<dim3(DMODEL * DMODEL / 1024), 256, 0, stream>>>(Wo, wo16, DMODEL * DMODEL / 4);
  cvt_kernel<<<dim3(DFFN * DMODEL / 1024), 256, 0, stream>>>(W1, w116, DFFN * DMODEL / 4);
  cvt_kernel<<<dim3(DMODEL * DFFN / 1024), 256, 0, stream>>>(W2, w216, DMODEL * DFFN / 4);
  cvtc_kernel<<<dim3(NTOK / 256), 256, 0, stream>>>(coords, cfl, NTOK);

  dim3 gQKV(NTOK / 128, DMODEL / 128);
  gemm_bt<0><<<gQKV, 256, 0, stream>>>(fb16, wq16, NTOK, DMODEL, DMODEL, nullptr, nullptr, nullptr, q16);
  gemm_bt<0><<<gQKV, 256, 0, stream>>>(fb16, wk16, NTOK, DMODEL, DMODEL, nullptr, nullptr, nullptr, k16);
  gemm_bt<0><<<gQKV, 256, 0, stream>>>(fb16, wv16, NTOK, DMODEL, DMODEL, nullptr, nullptr, nullptr, v16);
  transpose_kernel<<<dim3(NTOK / 64, DMODEL / 64), 256, 0, stream>>>(v16, vt16);
  attn6_kernel<<<dim3(NTOK / 32 * NHEAD), 128, 0, stream>>>(q16, k16, vt16, cfl, att16);
  gemm_bt<1><<<gQKV, 256, 0, stream>>>(att16, wo16, NTOK, DMODEL, DMODEL, bo, features, acc1, nullptr);
  ln_kernel<<<dim3(NTOK), 256, 0, stream>>>(acc1, ln1g, ln1b, xf, x16);
  gemm_bt<2><<<dim3(NTOK / 128, DFFN / 128), 256, 0, stream>>>(x16, w116, NTOK, DFFN, DMODEL, b1, nullptr, nullptr, h16);
  gemm_bt<3><<<gQKV, 256, 0, stream>>>(h16, w216, NTOK, DMODEL, DFFN, b2, xf, acc1, nullptr);
  ln_kernel<<<dim3(NTOK), 256, 0, stream>>>(acc1, ln2g, ln2b, outp, nullptr);
}